// Round 1
// baseline (13662.819 us; speedup 1.0000x reference)
//
#include <hip/hip_runtime.h>

#define NB 8
#define NE 1536
#define NHID 256
#define NHEAD 8
#define HDIM 32
#define LSEQ 50
#define NV 50257
#define NLAY 4
#define NFF 2048
#define BOSTOK 50256
#define LNEPS 1e-5f
#define NSTEP 49
#define FCT 786  // ceil(NV/64)

// workspace float offsets
#define WS_MEM 0
#define WS_CA  2048
#define WS_X   10240
#define WS_Q   12288
#define WS_FFP 14336
#define WS_KC  79872
#define WS_VC  489472
#define WS_PV  899072
#define WS_PI  905472
#define WS_TOK 911872

__device__ __forceinline__ float block_ln(float v, int tid, float* red, float* red2,
                                          float g, float bta) {
  red[tid] = v; red2[tid] = v * v;
  __syncthreads();
  for (int off = 128; off > 0; off >>= 1) {
    if (tid < off) { red[tid] += red[tid + off]; red2[tid] += red2[tid + off]; }
    __syncthreads();
  }
  float m = red[0] * (1.0f / 256.0f);
  float var = red2[0] * (1.0f / 256.0f) - m * m;
  float rs = rsqrtf(var + LNEPS);
  float y = (v - m) * rs * g + bta;
  __syncthreads();  // allow red reuse
  return y;
}

// ---- one-time init kernels ----

// mem[b][256] = embedding[b] @ w_proj.T + b_proj    grid 64 (b*8+tile), block 256
__global__ __launch_bounds__(256) void k_mem(const float* __restrict__ emb,
                                             const float* __restrict__ w,
                                             const float* __restrict__ bias,
                                             float* __restrict__ mem) {
  __shared__ float el[1536];
  __shared__ float red[256];
  int b = blockIdx.x >> 3, tile = blockIdx.x & 7, tid = threadIdx.x;
  for (int k = tid; k < 1536; k += 256) el[k] = emb[b * 1536 + k];
  __syncthreads();
  int r = tid >> 3, g = tid & 7;
  int row = tile * 32 + r;
  float acc = 0.f;
  const float* wr = w + row * 1536;
  for (int c = g * 192; c < g * 192 + 192; ++c) acc += wr[c] * el[c];
  red[tid] = acc;
  __syncthreads();
  for (int off = 4; off >= 1; off >>= 1) {
    if (g < off) red[tid] += red[tid + off];
    __syncthreads();
  }
  if (g == 0) mem[b * 256 + row] = red[tid] + bias[row];
}

// ca_const[l][b][256] = (mem[b]@Wv_ca.T+bv) @ ca_out_w.T + ca_out_b   grid 32 (l*8+b)
__global__ __launch_bounds__(256) void k_ca(const float* __restrict__ mem,
                                            const float* __restrict__ iw,
                                            const float* __restrict__ ib,
                                            const float* __restrict__ ow,
                                            const float* __restrict__ ob,
                                            float* __restrict__ ca) {
  __shared__ float ml[256], vl[256];
  int l = blockIdx.x >> 3, b = blockIdx.x & 7, tid = threadIdx.x;
  ml[tid] = mem[b * 256 + tid];
  __syncthreads();
  float acc = ib[l * 768 + 512 + tid];
  const float* wr = iw + (size_t)(l * 768 + 512 + tid) * 256;
  for (int c = 0; c < 256; ++c) acc += wr[c] * ml[c];
  vl[tid] = acc;
  __syncthreads();
  float acc2 = ob[l * 256 + tid];
  const float* wr2 = ow + (size_t)(l * 256 + tid) * 256;
  for (int c = 0; c < 256; ++c) acc2 += wr2[c] * vl[c];
  ca[(l * 8 + b) * 256 + tid] = acc2;
}

__global__ void k_tok_init(int* __restrict__ tok) {
  if (threadIdx.x < 8) tok[threadIdx.x * 64] = BOSTOK;
}

// ---- per-step kernels ----

// x[b][256] = tok_emb[tok[b][t]] + pos_enc[t]   grid 1, block 256
__global__ __launch_bounds__(256) void k_embed(const int* __restrict__ tok,
                                               const float* __restrict__ te,
                                               const float* __restrict__ pe,
                                               float* __restrict__ x, int t) {
  int tid = threadIdx.x;
  for (int b = 0; b < 8; ++b) {
    int tk = tok[b * 64 + t];
    x[b * 256 + tid] = te[(size_t)tk * 256 + tid] + pe[t * 256 + tid];
  }
}

// qkv GEMV: rows 0..767; q rows -> q buf, k/v rows -> caches at pos t.  grid 24, block 256
__global__ __launch_bounds__(256) void k_qkv(const float* __restrict__ x,
                                             const float* __restrict__ w,
                                             const float* __restrict__ bias,
                                             float* __restrict__ q,
                                             float* __restrict__ kc,
                                             float* __restrict__ vc, int l, int t) {
  __shared__ float xl[8 * 260];
  int tid = threadIdx.x;
  for (int k = 0; k < 8; ++k) {
    int idx = tid + k * 256;
    xl[(idx >> 8) * 260 + (idx & 255)] = x[idx];
  }
  __syncthreads();
  int r = tid >> 3, b = tid & 7;
  int row = blockIdx.x * 32 + r;
  float acc = bias[l * 768 + row];
  const float4* w4 = reinterpret_cast<const float4*>(w + (size_t)(l * 768 + row) * 256);
  const float4* xv = reinterpret_cast<const float4*>(xl + b * 260);
#pragma unroll 8
  for (int k = 0; k < 64; ++k) {
    float4 wv = w4[k]; float4 xq = xv[k];
    acc += wv.x * xq.x + wv.y * xq.y + wv.z * xq.z + wv.w * xq.w;
  }
  if (row < 256) {
    q[b * 256 + row] = acc;
  } else if (row < 512) {
    int h = (row - 256) >> 5, d = (row - 256) & 31;
    kc[(((l * 8 + b) * 8 + h) * 50 + t) * 32 + d] = acc;
  } else {
    int h = (row - 512) >> 5, d = (row - 512) & 31;
    vc[(((l * 8 + b) * 8 + h) * 50 + t) * 32 + d] = acc;
  }
}

// attention + out-proj + residual + LN + ca_const + LN.  grid 8 (b), block 256
__global__ __launch_bounds__(256) void k_attn(const float* __restrict__ q,
                                              float* __restrict__ x,
                                              const float* __restrict__ kc,
                                              const float* __restrict__ vc,
                                              const float* __restrict__ ow,
                                              const float* __restrict__ ob,
                                              const float* __restrict__ lg,
                                              const float* __restrict__ lb,
                                              const float* __restrict__ ca, int l, int t) {
  __shared__ float ql[256], ol[256], sc[64], red[256], red2[256];
  __shared__ float ssum;
  int b = blockIdx.x, tid = threadIdx.x;
  float xres = x[b * 256 + tid];
  ql[tid] = q[b * 256 + tid];
  __syncthreads();
  for (int h = 0; h < 8; ++h) {
    const float* kb = kc + (size_t)(((l * 8 + b) * 8 + h) * 50) * 32;
    if (tid <= t) {  // t <= 48 < 50
      float s = 0.f;
      const float* kr = kb + tid * 32;
#pragma unroll
      for (int d = 0; d < 32; ++d) s += ql[h * 32 + d] * kr[d];
      sc[tid] = s * 0.17677669529663687f;  // 1/sqrt(32)
    }
    __syncthreads();
    if (tid < 64) {
      float v = (tid <= t) ? sc[tid] : -1e30f;
      float mx = v;
      for (int m = 32; m >= 1; m >>= 1) mx = fmaxf(mx, __shfl_xor(mx, m));
      float e = (tid <= t) ? expf(sc[tid] - mx) : 0.f;
      sc[tid] = e;
      float sm = e;
      for (int m = 32; m >= 1; m >>= 1) sm += __shfl_xor(sm, m);
      if (tid == 0) ssum = sm;
    }
    __syncthreads();
    if (tid < 32) {
      const float* vb = vc + (size_t)(((l * 8 + b) * 8 + h) * 50) * 32 + tid;
      float acc = 0.f;
      for (int j = 0; j <= t; ++j) acc += sc[j] * vb[j * 32];
      ol[h * 32 + tid] = acc / ssum;
    }
    __syncthreads();
  }
  // out-proj row = tid
  float acc = ob[l * 256 + tid];
  const float4* w4 = reinterpret_cast<const float4*>(ow + (size_t)(l * 256 + tid) * 256);
#pragma unroll 4
  for (int k = 0; k < 64; ++k) {
    float4 wv = w4[k];
    acc += wv.x * ol[4 * k] + wv.y * ol[4 * k + 1] + wv.z * ol[4 * k + 2] + wv.w * ol[4 * k + 3];
  }
  acc += xres;
  float y = block_ln(acc, tid, red, red2, lg[(l * 3 + 0) * 256 + tid], lb[(l * 3 + 0) * 256 + tid]);
  float acc2 = y + ca[(l * 8 + b) * 256 + tid];
  float y2 = block_ln(acc2, tid, red, red2, lg[(l * 3 + 1) * 256 + tid], lb[(l * 3 + 1) * 256 + tid]);
  x[b * 256 + tid] = y2;
}

// fused FFN slice: h1 = relu(x@W1.T+b1) for 64 neurons, partial ff2 contribution.
// grid 32 (slice), block 256
__global__ __launch_bounds__(256) void k_ffn(const float* __restrict__ x,
                                             const float* __restrict__ w1,
                                             const float* __restrict__ b1,
                                             const float* __restrict__ w2,
                                             float* __restrict__ ffp, int l) {
  __shared__ float xl[8 * 260];
  __shared__ float h1l[64 * 9];
  int tid = threadIdx.x, s = blockIdx.x;
  for (int k = 0; k < 8; ++k) {
    int idx = tid + k * 256;
    xl[(idx >> 8) * 260 + (idx & 255)] = x[idx];
  }
  __syncthreads();
  int n0 = tid >> 3, b = tid & 7;
#pragma unroll
  for (int i = 0; i < 2; ++i) {
    int nn = n0 + i * 32, row = s * 64 + nn;
    float acc = b1[l * 2048 + row];
    const float4* w4 = reinterpret_cast<const float4*>(w1 + (size_t)(l * 2048 + row) * 256);
    const float4* xv = reinterpret_cast<const float4*>(xl + b * 260);
    for (int k = 0; k < 64; ++k) {
      float4 wv = w4[k]; float4 xq = xv[k];
      acc += wv.x * xq.x + wv.y * xq.y + wv.z * xq.z + wv.w * xq.w;
    }
    h1l[nn * 9 + b] = fmaxf(acc, 0.f);
  }
  __syncthreads();
  int row = tid;
  float acc[8] = {0, 0, 0, 0, 0, 0, 0, 0};
  const float* w2p = w2 + (size_t)(l * 256 + row) * 2048 + s * 64;
  for (int n = 0; n < 64; ++n) {
    float wv = w2p[n];
#pragma unroll
    for (int b2 = 0; b2 < 8; ++b2) acc[b2] += wv * h1l[n * 9 + b2];
  }
  for (int b2 = 0; b2 < 8; ++b2) ffp[(s * 8 + b2) * 256 + row] = acc[b2];
}

// reduce ffn partials + bias + residual + LN.  grid 8 (b), block 256
__global__ __launch_bounds__(256) void k_ffred(float* __restrict__ x,
                                               const float* __restrict__ ffp,
                                               const float* __restrict__ b2,
                                               const float* __restrict__ lg,
                                               const float* __restrict__ lb, int l) {
  __shared__ float red[256], red2[256];
  int b = blockIdx.x, tid = threadIdx.x;
  float acc = b2[l * 256 + tid] + x[b * 256 + tid];
  for (int s = 0; s < 32; ++s) acc += ffp[(s * 8 + b) * 256 + tid];
  float y = block_ln(acc, tid, red, red2, lg[(l * 3 + 2) * 256 + tid], lb[(l * 3 + 2) * 256 + tid]);
  x[b * 256 + tid] = y;
}

// vocab head: 64 rows/WG x 8 batches; writes logits and per-WG argmax partials.
// grid 786, block 256
__global__ __launch_bounds__(256) void k_fc(const float* __restrict__ h,
                                            const float* __restrict__ w,
                                            const float* __restrict__ bias,
                                            float* __restrict__ out,
                                            float* __restrict__ pv,
                                            int* __restrict__ pi, int t) {
  __shared__ float hl[8 * 260];
  __shared__ float rv[256];
  __shared__ int ri[256];
  int tid = threadIdx.x, wg = blockIdx.x;
  for (int k = 0; k < 8; ++k) {
    int idx = tid + k * 256;
    hl[(idx >> 8) * 260 + (idx & 255)] = h[idx];
  }
  __syncthreads();
  int r = tid >> 3, b = tid & 7;
  float bv = -3e38f;
  int bi = 2147483647;
  for (int i = 0; i < 2; ++i) {
    int row = wg * 64 + i * 32 + r;
    if (row < NV) {
      float acc = bias[row];
      const float4* w4 = reinterpret_cast<const float4*>(w + (size_t)row * 256);
      const float4* xv = reinterpret_cast<const float4*>(hl + b * 260);
      for (int k = 0; k < 64; ++k) {
        float4 wv = w4[k]; float4 xq = xv[k];
        acc += wv.x * xq.x + wv.y * xq.y + wv.z * xq.z + wv.w * xq.w;
      }
      out[(size_t)(b * 49 + t) * NV + row] = acc;
      if (acc > bv || (acc == bv && row < bi)) { bv = acc; bi = row; }
    }
  }
  rv[tid] = bv; ri[tid] = bi;
  __syncthreads();
  for (int off = 128; off >= 8; off >>= 1) {
    if (tid < off) {
      float v = rv[tid + off]; int id = ri[tid + off];
      if (v > rv[tid] || (v == rv[tid] && id < ri[tid])) { rv[tid] = v; ri[tid] = id; }
    }
    __syncthreads();
  }
  if (tid < 8) { pv[wg * 8 + tid] = rv[tid]; pi[wg * 8 + tid] = ri[tid]; }
}

// final argmax over 786 partials per batch; write tokens[b][t+1].  grid 1, block 256
__global__ __launch_bounds__(256) void k_amax(const float* __restrict__ pv,
                                              const int* __restrict__ pi,
                                              int* __restrict__ tok, int t) {
  __shared__ float rv[256];
  __shared__ int ri[256];
  int tid = threadIdx.x, b = tid & 7, i0 = tid >> 3;
  float bv = -3e38f;
  int bi = 2147483647;
  for (int p = i0; p < FCT; p += 32) {
    float v = pv[p * 8 + b]; int id = pi[p * 8 + b];
    if (v > bv || (v == bv && id < bi)) { bv = v; bi = id; }
  }
  rv[tid] = bv; ri[tid] = bi;
  __syncthreads();
  for (int off = 128; off >= 8; off >>= 1) {
    if (tid < off) {
      float v = rv[tid + off]; int id = ri[tid + off];
      if (v > rv[tid] || (v == rv[tid] && id < ri[tid])) { rv[tid] = v; ri[tid] = id; }
    }
    __syncthreads();
  }
  if (tid < 8) tok[tid * 64 + t + 1] = ri[tid];
}

extern "C" void kernel_launch(void* const* d_in, const int* in_sizes, int n_in,
                              void* d_out, int out_size, void* d_ws, size_t ws_size,
                              hipStream_t stream) {
  (void)in_sizes; (void)n_in; (void)out_size; (void)ws_size;
  const float* embedding = (const float*)d_in[0];
  const float* w_proj   = (const float*)d_in[1];
  const float* b_proj   = (const float*)d_in[2];
  const float* tok_emb  = (const float*)d_in[3];
  const float* pos_enc  = (const float*)d_in[4];
  const float* sa_in_w  = (const float*)d_in[5];
  const float* sa_in_b  = (const float*)d_in[6];
  const float* sa_out_w = (const float*)d_in[7];
  const float* sa_out_b = (const float*)d_in[8];
  const float* ca_in_w  = (const float*)d_in[9];
  const float* ca_in_b  = (const float*)d_in[10];
  const float* ca_out_w = (const float*)d_in[11];
  const float* ca_out_b = (const float*)d_in[12];
  const float* ff1_w    = (const float*)d_in[13];
  const float* ff1_b    = (const float*)d_in[14];
  const float* ff2_w    = (const float*)d_in[15];
  const float* ff2_b    = (const float*)d_in[16];
  const float* ln_g     = (const float*)d_in[17];
  const float* ln_b     = (const float*)d_in[18];
  const float* fc_w     = (const float*)d_in[19];
  const float* fc_b     = (const float*)d_in[20];

  float* ws  = (float*)d_ws;
  float* out = (float*)d_out;
  float* mem = ws + WS_MEM;
  float* ca  = ws + WS_CA;
  float* x   = ws + WS_X;
  float* q   = ws + WS_Q;
  float* ffp = ws + WS_FFP;
  float* kc  = ws + WS_KC;
  float* vc  = ws + WS_VC;
  float* pv  = ws + WS_PV;
  int*   pi  = (int*)d_ws + WS_PI;
  int*   tok = (int*)d_ws + WS_TOK;

  k_mem<<<64, 256, 0, stream>>>(embedding, w_proj, b_proj, mem);
  k_ca<<<32, 256, 0, stream>>>(mem, ca_in_w, ca_in_b, ca_out_w, ca_out_b, ca);
  k_tok_init<<<1, 64, 0, stream>>>(tok);

  for (int t = 0; t < NSTEP; ++t) {
    k_embed<<<1, 256, 0, stream>>>(tok, tok_emb, pos_enc, x, t);
    for (int l = 0; l < NLAY; ++l) {
      k_qkv<<<24, 256, 0, stream>>>(x, sa_in_w, sa_in_b, q, kc, vc, l, t);
      k_attn<<<8, 256, 0, stream>>>(q, x, kc, vc, sa_out_w, sa_out_b, ln_g, ln_b, ca, l, t);
      k_ffn<<<32, 256, 0, stream>>>(x, ff1_w, ff1_b, ff2_w, ffp, l);
      k_ffred<<<8, 256, 0, stream>>>(x, ffp, ff2_b, ln_g, ln_b, l);
    }
    k_fc<<<FCT, 256, 0, stream>>>(x, fc_w, fc_b, out, pv, pi, t);
    k_amax<<<1, 256, 0, stream>>>(pv, pi, tok, t);
  }
}